// Round 9
// baseline (39.000 us; speedup 1.0000x reference)
//
#include <hip/hip_runtime.h>
#include <hip/hip_bf16.h>

#define N_ATOMS 51200

// Output layout (flat floats, reference return order):
//   energy[512]@0, forces[153600]@512, stress[4608]@154112,
//   energy_uncert[512]@158720 (=0.6), force_uncert[153600]@159232 (computed),
//   stress_uncert[4608]@312832 (=0.1/16)
#define OUT_FUNC 159232

typedef __attribute__((ext_vector_type(4))) float f32x4;
typedef __attribute__((ext_vector_type(4))) short s16x4;
typedef __attribute__((ext_vector_type(8))) short s16x8;

constexpr int BLK = 256;

__device__ __forceinline__ short f2bf(float x) {
    union { __hip_bfloat16 b; short s; } u;
    u.b = __float2bfloat16(x);            // RNE
    return u.s;
}
__device__ __forceinline__ float silu_(float v) { return v / (1.0f + __expf(-v)); }
__device__ __forceinline__ s16x8 cvt8(f32x4 lo, f32x4 hi) {
    s16x8 f;
    f[0]=f2bf(lo.x); f[1]=f2bf(lo.y); f[2]=f2bf(lo.z); f[3]=f2bf(lo.w);
    f[4]=f2bf(hi.x); f[5]=f2bf(hi.y); f[6]=f2bf(hi.z); f[7]=f2bf(hi.w);
    return f;
}

__global__ __launch_bounds__(BLK, 5) void funcert_kernel(
    const float* __restrict__ nf,
    const float* __restrict__ energy,
    const float* __restrict__ forces,
    const float* __restrict__ stress,
    const float* __restrict__ W1f, const float* __restrict__ b1f,
    const float* __restrict__ W2f, const float* __restrict__ b2f,
    const float* __restrict__ W3f, const float* __restrict__ b3f,
    float* __restrict__ out)
{
    const int t   = threadIdx.x;
    const int gid = blockIdx.x * BLK + t;

    __shared__ short Xs[64 * 128];   // 16 KB: half-K X tile bf16 (64 x 128), swizzled 16B slots
    __shared__ short H1s[64 * 64];   // 8 KB: h1 bf16, row=atom (128B)

    const int lane  = t & 63;
    const int w     = t >> 6;
    const int g     = lane >> 4;     // k-subgroup
    const int col   = lane & 15;     // A row / B col / D col
    const int abase = blockIdx.x * 64;

    const int ch  = w * 16 + col;
    const int c4  = lane & 31;       // f4 column within the half-row
    const int sub = lane >> 5;       // row-pair sub-index
    const int spb = c4 >> 1;         // 16B-slot base (^ (r&7) per row)

    // ---- issue W0 loads first (arrive while X0 in flight) ----
    f32x4 wv[8];
    #pragma unroll
    for (int ks = 0; ks < 4; ++ks) {
        const float* p = W1f + ch * 256 + ks * 32 + g * 8;
        wv[2 * ks]     = *(const f32x4*)p;
        wv[2 * ks + 1] = *(const f32x4*)(p + 4);
    }

    // ---- issue X0 staging loads ----
    f32x4 xv[8];
    #pragma unroll
    for (int i = 0; i < 8; ++i) {
        const int r = i * 8 + w * 2 + sub;
        xv[i] = ((const f32x4*)nf)[(size_t)(abase + r) * 96 + c4];      // half 0
    }

    // ---- passthrough / constant outputs as float4 (overlaps with loads) ----
    if (gid < 40960) {
        f32x4 v; int o = gid;
        if      (gid < 128)   { v = ((const f32x4*)energy)[gid]; }
        else if (gid < 38528) { v = ((const f32x4*)forces)[gid - 128]; }
        else if (gid < 39680) { v = ((const f32x4*)stress)[gid - 38528]; }
        else if (gid < 39808) { v = (f32x4){0.6f, 0.6f, 0.6f, 0.6f}; }
        else { v = (f32x4){0.00625f, 0.00625f, 0.00625f, 0.00625f}; o = gid + 38400; }
        ((f32x4*)out)[o] = v;
    }

    const float b1v = b1f[ch];

    // ---- cvt W0 -> wf0 (frees wv before xv1 goes live) ----
    s16x8 wf0[4];
    #pragma unroll
    for (int ks = 0; ks < 4; ++ks) wf0[ks] = cvt8(wv[2 * ks], wv[2 * ks + 1]);

    // ---- cvt X0 + swizzled LDS write ----
    #pragma unroll
    for (int i = 0; i < 8; ++i) {
        const int r  = i * 8 + w * 2 + sub;
        const int sp = spb ^ (r & 7);
        s16x4 bb;
        bb.x = f2bf(xv[i].x); bb.y = f2bf(xv[i].y);
        bb.z = f2bf(xv[i].z); bb.w = f2bf(xv[i].w);
        *(s16x4*)(Xs + r * 128 + sp * 8 + (lane & 1) * 4) = bb;
    }
    __syncthreads();                 // (1) Xs = half 0 ready

    // ---- issue X1 loads NOW: latency hides under half-0 compute ----
    #pragma unroll
    for (int i = 0; i < 8; ++i) {
        const int r = i * 8 + w * 2 + sub;
        xv[i] = ((const f32x4*)nf)[(size_t)(abase + r) * 96 + 64 + c4]; // half 1
    }

    // ---- compute half 0: 4 M-tiles x 4 k-steps ----
    f32x4 acc[4];
    #pragma unroll
    for (int mt = 0; mt < 4; ++mt) acc[mt] = (f32x4){0.f, 0.f, 0.f, 0.f};
    #pragma unroll
    for (int mt = 0; mt < 4; ++mt) {
        const int row = mt * 16 + col;
        #pragma unroll
        for (int ks = 0; ks < 4; ++ks) {
            const int sl = (ks * 4 + g) ^ (row & 7);
            const s16x8 af = *(const s16x8*)(Xs + row * 128 + sl * 8);
            acc[mt] = __builtin_amdgcn_mfma_f32_16x16x32_bf16(af, wf0[ks], acc[mt], 0, 0, 0);
        }
    }
    __syncthreads();                 // (2) all waves done reading half 0

    // ---- W1 loads (hidden under X1 cvt/write + barrier) ----
    #pragma unroll
    for (int ks = 0; ks < 4; ++ks) {
        const float* p = W1f + ch * 256 + 128 + ks * 32 + g * 8;
        wv[2 * ks]     = *(const f32x4*)p;
        wv[2 * ks + 1] = *(const f32x4*)(p + 4);
    }

    // ---- cvt X1 + swizzled LDS write (overwrites Xs) ----
    #pragma unroll
    for (int i = 0; i < 8; ++i) {
        const int r  = i * 8 + w * 2 + sub;
        const int sp = spb ^ (r & 7);
        s16x4 bb;
        bb.x = f2bf(xv[i].x); bb.y = f2bf(xv[i].y);
        bb.z = f2bf(xv[i].z); bb.w = f2bf(xv[i].w);
        *(s16x4*)(Xs + r * 128 + sp * 8 + (lane & 1) * 4) = bb;
    }
    s16x8 wf1[4];
    #pragma unroll
    for (int ks = 0; ks < 4; ++ks) wf1[ks] = cvt8(wv[2 * ks], wv[2 * ks + 1]);
    __syncthreads();                 // (3) Xs = half 1 ready

    // ---- compute half 1 ----
    #pragma unroll
    for (int mt = 0; mt < 4; ++mt) {
        const int row = mt * 16 + col;
        #pragma unroll
        for (int ks = 0; ks < 4; ++ks) {
            const int sl = (ks * 4 + g) ^ (row & 7);
            const s16x8 af = *(const s16x8*)(Xs + row * 128 + sl * 8);
            acc[mt] = __builtin_amdgcn_mfma_f32_16x16x32_bf16(af, wf1[ks], acc[mt], 0, 0, 0);
        }
    }

    // ---- bias + silu -> h1 (layout identical to R3/R7) ----
    #pragma unroll
    for (int mt = 0; mt < 4; ++mt) {
        #pragma unroll
        for (int r = 0; r < 4; ++r) {
            const int atom = mt * 16 + g * 4 + r;
            H1s[atom * 64 + ch] = f2bf(silu_(acc[mt][r] + b1v));
        }
    }
    __syncthreads();

    // ---- L2: wave w -> atoms [16w,16w+16), 2 k-steps over 64 ch ----
    s16x8 w2frag[2];
    #pragma unroll
    for (int ks = 0; ks < 2; ++ks) {
        const float* p = W2f + col * 64 + ks * 32 + g * 8;   // B2[k][n] = W2f[n][k]
        w2frag[ks] = cvt8(*(const f32x4*)p, *(const f32x4*)(p + 4));
    }
    const int arow = w * 16 + col;
    f32x4 a2 = {0.f, 0.f, 0.f, 0.f};
    #pragma unroll
    for (int ks = 0; ks < 2; ++ks) {
        const s16x8 af = *(const s16x8*)(H1s + arow * 64 + ks * 32 + g * 8);
        a2 = __builtin_amdgcn_mfma_f32_16x16x32_bf16(af, w2frag[ks], a2, 0, 0, 0);
    }

    // ---- h2 + L3 + exp: lane owns ch2=col for atoms 16w + g*4 + r ----
    const float b2v = b2f[col];
    const float w3v = W3f[col];
    float y[4];
    #pragma unroll
    for (int r = 0; r < 4; ++r)
        y[r] = silu_(a2[r] + b2v) * w3v;
    #pragma unroll
    for (int m = 1; m < 16; m <<= 1) {
        #pragma unroll
        for (int r = 0; r < 4; ++r)
            y[r] += __shfl_xor(y[r], m, 64);   // reduce over 16 cols
    }
    const float b3v = b3f[0];
    float fu[4];
    #pragma unroll
    for (int r = 0; r < 4; ++r)
        fu[r] = __expf(y[r] + b3v) * 0.1f;

    if (col < 12) {                            // 4 atoms x 3 comps per 16-lane group
        const int a_ = col / 3, c = col - a_ * 3;
        const float v = (a_ == 0) ? fu[0] : (a_ == 1) ? fu[1] : (a_ == 2) ? fu[2] : fu[3];
        const int atom = w * 16 + g * 4 + a_;
        out[OUT_FUNC + 3 * (abase + atom) + c] = v;
    }
}

extern "C" void kernel_launch(void* const* d_in, const int* in_sizes, int n_in,
                              void* d_out, int out_size, void* d_ws, size_t ws_size,
                              hipStream_t stream) {
    const float* nf     = (const float*)d_in[0];
    const float* energy = (const float*)d_in[1];
    const float* forces = (const float*)d_in[2];
    const float* stress = (const float*)d_in[3];
    const float* W1f    = (const float*)d_in[10];
    const float* b1f    = (const float*)d_in[11];
    const float* W2f    = (const float*)d_in[12];
    const float* b2f    = (const float*)d_in[13];
    const float* W3f    = (const float*)d_in[14];
    const float* b3f    = (const float*)d_in[15];
    float* out = (float*)d_out;

    dim3 grid(N_ATOMS / 64);   // 800 blocks

    // DIAGNOSTIC ROUND: launch the identical kernel TWICE (idempotent -> same
    // final output). Replay time = K1 + K2 + O vs R8's K + O; comparing with
    // R8's 21.8 us decomposes fixed per-replay overhead O from kernel time K.
    funcert_kernel<<<grid, BLK, 0, stream>>>(nf, energy, forces, stress,
                                             W1f, b1f, W2f, b2f, W3f, b3f, out);
    funcert_kernel<<<grid, BLK, 0, stream>>>(nf, energy, forces, stress,
                                             W1f, b1f, W2f, b2f, W3f, b3f, out);
}

// Round 10
// 21.929 us; speedup vs baseline: 1.7785x; 1.7785x over previous
//
#include <hip/hip_runtime.h>
#include <hip/hip_bf16.h>

#define N_ATOMS 51200

// Output layout (flat floats, reference return order):
//   energy[512]@0, forces[153600]@512, stress[4608]@154112,
//   energy_uncert[512]@158720 (=0.6), force_uncert[153600]@159232 (computed),
//   stress_uncert[4608]@312832 (=0.1/16)
#define OUT_FUNC 159232

typedef __attribute__((ext_vector_type(4))) float f32x4;
typedef __attribute__((ext_vector_type(2))) unsigned u32x2;
typedef __attribute__((ext_vector_type(4))) unsigned u32x4;
typedef __attribute__((ext_vector_type(8))) short s16x8;

constexpr int BLK = 256;

// Truncating f32->bf16 pair pack: D = [hi.trunc16, lo.trunc16], 1 VALU op.
// sel 0x07060302: D.b3=S0.b3, D.b2=S0.b2 (hi), D.b1=S1.b3, D.b0=S1.b2 (lo).
__device__ __forceinline__ unsigned pack2(float lo, float hi) {
    return __builtin_amdgcn_perm(__float_as_uint(hi), __float_as_uint(lo), 0x07060302);
}
__device__ __forceinline__ s16x8 pack8(f32x4 lo, f32x4 hi) {
    union { u32x4 u; s16x8 s; } c;
    c.u.x = pack2(lo.x, lo.y); c.u.y = pack2(lo.z, lo.w);
    c.u.z = pack2(hi.x, hi.y); c.u.w = pack2(hi.z, hi.w);
    return c.s;
}
__device__ __forceinline__ short bftrunc(float x) {
    return (short)(__float_as_uint(x) >> 16);
}
__device__ __forceinline__ float silu_(float v) { return v / (1.0f + __expf(-v)); }

__global__ __launch_bounds__(BLK, 5) void funcert_kernel(
    const float* __restrict__ nf,
    const float* __restrict__ energy,
    const float* __restrict__ forces,
    const float* __restrict__ stress,
    const float* __restrict__ W1f, const float* __restrict__ b1f,
    const float* __restrict__ W2f, const float* __restrict__ b2f,
    const float* __restrict__ W3f, const float* __restrict__ b3f,
    float* __restrict__ out)
{
    const int t   = threadIdx.x;
    const int gid = blockIdx.x * BLK + t;

    __shared__ short Xs[64 * 128];   // 16 KB: half-K X tile bf16 (64 x 128), swizzled 16B slots
    __shared__ short H1s[64 * 64];   // 8 KB: h1 bf16, row=atom (128B)

    const int lane  = t & 63;
    const int w     = t >> 6;
    const int g     = lane >> 4;     // k-subgroup
    const int col   = lane & 15;     // A row / B col / D col
    const int abase = blockIdx.x * 64;

    const int ch  = w * 16 + col;
    const int c4  = lane & 31;       // f4 column within the half-row
    const int sub = lane >> 5;       // row-pair sub-index
    const int spb = c4 >> 1;         // 16B-slot base (^ (r&7) per row)

    // ---- issue W0 loads first (arrive while X0 in flight) ----
    f32x4 wv[8];
    #pragma unroll
    for (int ks = 0; ks < 4; ++ks) {
        const float* p = W1f + ch * 256 + ks * 32 + g * 8;
        wv[2 * ks]     = *(const f32x4*)p;
        wv[2 * ks + 1] = *(const f32x4*)(p + 4);
    }

    // ---- issue X0 staging loads ----
    f32x4 xv[8];
    #pragma unroll
    for (int i = 0; i < 8; ++i) {
        const int r = i * 8 + w * 2 + sub;
        xv[i] = ((const f32x4*)nf)[(size_t)(abase + r) * 96 + c4];      // half 0
    }

    // ---- passthrough / constant outputs as float4 (overlaps with loads) ----
    if (gid < 40960) {
        f32x4 v; int o = gid;
        if      (gid < 128)   { v = ((const f32x4*)energy)[gid]; }
        else if (gid < 38528) { v = ((const f32x4*)forces)[gid - 128]; }
        else if (gid < 39680) { v = ((const f32x4*)stress)[gid - 38528]; }
        else if (gid < 39808) { v = (f32x4){0.6f, 0.6f, 0.6f, 0.6f}; }
        else { v = (f32x4){0.00625f, 0.00625f, 0.00625f, 0.00625f}; o = gid + 38400; }
        ((f32x4*)out)[o] = v;
    }

    const float b1v = b1f[ch];

    // ---- pack W0 -> wf0 (1 perm per 2 elems; frees wv before xv1 goes live) ----
    s16x8 wf0[4];
    #pragma unroll
    for (int ks = 0; ks < 4; ++ks) wf0[ks] = pack8(wv[2 * ks], wv[2 * ks + 1]);

    // ---- pack X0 + swizzled LDS write ----
    #pragma unroll
    for (int i = 0; i < 8; ++i) {
        const int r  = i * 8 + w * 2 + sub;
        const int sp = spb ^ (r & 7);
        u32x2 bb;
        bb.x = pack2(xv[i].x, xv[i].y);
        bb.y = pack2(xv[i].z, xv[i].w);
        *(u32x2*)(Xs + r * 128 + sp * 8 + (lane & 1) * 4) = bb;
    }
    __syncthreads();                 // (1) Xs = half 0 ready

    // ---- issue X1 loads NOW: latency hides under half-0 compute ----
    #pragma unroll
    for (int i = 0; i < 8; ++i) {
        const int r = i * 8 + w * 2 + sub;
        xv[i] = ((const f32x4*)nf)[(size_t)(abase + r) * 96 + 64 + c4]; // half 1
    }

    // ---- compute half 0: 4 M-tiles x 4 k-steps ----
    f32x4 acc[4];
    #pragma unroll
    for (int mt = 0; mt < 4; ++mt) acc[mt] = (f32x4){0.f, 0.f, 0.f, 0.f};
    #pragma unroll
    for (int mt = 0; mt < 4; ++mt) {
        const int row = mt * 16 + col;
        #pragma unroll
        for (int ks = 0; ks < 4; ++ks) {
            const int sl = (ks * 4 + g) ^ (row & 7);
            const s16x8 af = *(const s16x8*)(Xs + row * 128 + sl * 8);
            acc[mt] = __builtin_amdgcn_mfma_f32_16x16x32_bf16(af, wf0[ks], acc[mt], 0, 0, 0);
        }
    }
    __syncthreads();                 // (2) all waves done reading half 0

    // ---- W1 loads (hidden under X1 pack/write + barrier) ----
    #pragma unroll
    for (int ks = 0; ks < 4; ++ks) {
        const float* p = W1f + ch * 256 + 128 + ks * 32 + g * 8;
        wv[2 * ks]     = *(const f32x4*)p;
        wv[2 * ks + 1] = *(const f32x4*)(p + 4);
    }

    // ---- pack X1 + swizzled LDS write (overwrites Xs) ----
    #pragma unroll
    for (int i = 0; i < 8; ++i) {
        const int r  = i * 8 + w * 2 + sub;
        const int sp = spb ^ (r & 7);
        u32x2 bb;
        bb.x = pack2(xv[i].x, xv[i].y);
        bb.y = pack2(xv[i].z, xv[i].w);
        *(u32x2*)(Xs + r * 128 + sp * 8 + (lane & 1) * 4) = bb;
    }
    s16x8 wf1[4];
    #pragma unroll
    for (int ks = 0; ks < 4; ++ks) wf1[ks] = pack8(wv[2 * ks], wv[2 * ks + 1]);
    __syncthreads();                 // (3) Xs = half 1 ready

    // ---- compute half 1 ----
    #pragma unroll
    for (int mt = 0; mt < 4; ++mt) {
        const int row = mt * 16 + col;
        #pragma unroll
        for (int ks = 0; ks < 4; ++ks) {
            const int sl = (ks * 4 + g) ^ (row & 7);
            const s16x8 af = *(const s16x8*)(Xs + row * 128 + sl * 8);
            acc[mt] = __builtin_amdgcn_mfma_f32_16x16x32_bf16(af, wf1[ks], acc[mt], 0, 0, 0);
        }
    }

    // ---- bias + silu -> h1 (trunc bf16; layout identical to R8) ----
    #pragma unroll
    for (int mt = 0; mt < 4; ++mt) {
        #pragma unroll
        for (int r = 0; r < 4; ++r) {
            const int atom = mt * 16 + g * 4 + r;
            H1s[atom * 64 + ch] = bftrunc(silu_(acc[mt][r] + b1v));
        }
    }
    __syncthreads();

    // ---- L2: wave w -> atoms [16w,16w+16), 2 k-steps over 64 ch ----
    s16x8 w2frag[2];
    #pragma unroll
    for (int ks = 0; ks < 2; ++ks) {
        const float* p = W2f + col * 64 + ks * 32 + g * 8;   // B2[k][n] = W2f[n][k]
        w2frag[ks] = pack8(*(const f32x4*)p, *(const f32x4*)(p + 4));
    }
    const int arow = w * 16 + col;
    f32x4 a2 = {0.f, 0.f, 0.f, 0.f};
    #pragma unroll
    for (int ks = 0; ks < 2; ++ks) {
        const s16x8 af = *(const s16x8*)(H1s + arow * 64 + ks * 32 + g * 8);
        a2 = __builtin_amdgcn_mfma_f32_16x16x32_bf16(af, w2frag[ks], a2, 0, 0, 0);
    }

    // ---- h2 + L3 + exp: lane owns ch2=col for atoms 16w + g*4 + r ----
    const float b2v = b2f[col];
    const float w3v = W3f[col];
    float y[4];
    #pragma unroll
    for (int r = 0; r < 4; ++r)
        y[r] = silu_(a2[r] + b2v) * w3v;
    #pragma unroll
    for (int m = 1; m < 16; m <<= 1) {
        #pragma unroll
        for (int r = 0; r < 4; ++r)
            y[r] += __shfl_xor(y[r], m, 64);   // reduce over 16 cols
    }
    const float b3v = b3f[0];
    float fu[4];
    #pragma unroll
    for (int r = 0; r < 4; ++r)
        fu[r] = __expf(y[r] + b3v) * 0.1f;

    if (col < 12) {                            // 4 atoms x 3 comps per 16-lane group
        const int a_ = col / 3, c = col - a_ * 3;
        const float v = (a_ == 0) ? fu[0] : (a_ == 1) ? fu[1] : (a_ == 2) ? fu[2] : fu[3];
        const int atom = w * 16 + g * 4 + a_;
        out[OUT_FUNC + 3 * (abase + atom) + c] = v;
    }
}

extern "C" void kernel_launch(void* const* d_in, const int* in_sizes, int n_in,
                              void* d_out, int out_size, void* d_ws, size_t ws_size,
                              hipStream_t stream) {
    const float* nf     = (const float*)d_in[0];
    const float* energy = (const float*)d_in[1];
    const float* forces = (const float*)d_in[2];
    const float* stress = (const float*)d_in[3];
    const float* W1f    = (const float*)d_in[10];
    const float* b1f    = (const float*)d_in[11];
    const float* W2f    = (const float*)d_in[12];
    const float* b2f    = (const float*)d_in[13];
    const float* W3f    = (const float*)d_in[14];
    const float* b3f    = (const float*)d_in[15];
    float* out = (float*)d_out;

    dim3 grid(N_ATOMS / 64);   // 800 blocks
    funcert_kernel<<<grid, BLK, 0, stream>>>(nf, energy, forces, stress,
                                             W1f, b1f, W2f, b2f, W3f, b3f, out);
}

// Round 11
// 20.892 us; speedup vs baseline: 1.8667x; 1.0496x over previous
//
#include <hip/hip_runtime.h>
#include <hip/hip_bf16.h>

#define N_ATOMS 51200

// Output layout (flat floats, reference return order):
//   energy[512]@0, forces[153600]@512, stress[4608]@154112,
//   energy_uncert[512]@158720 (=0.6), force_uncert[153600]@159232 (computed),
//   stress_uncert[4608]@312832 (=0.1/16)
#define OUT_FUNC 159232

typedef __attribute__((ext_vector_type(4))) float f32x4;
typedef __attribute__((ext_vector_type(2))) unsigned u32x2;
typedef __attribute__((ext_vector_type(4))) unsigned u32x4;
typedef __attribute__((ext_vector_type(8))) short s16x8;

constexpr int BLK = 256;

// Truncating f32->bf16 pair pack (1 v_perm each; verified numerically R10).
__device__ __forceinline__ unsigned pack2(float lo, float hi) {
    return __builtin_amdgcn_perm(__float_as_uint(hi), __float_as_uint(lo), 0x07060302);
}
__device__ __forceinline__ s16x8 pack8(f32x4 lo, f32x4 hi) {
    union { u32x4 u; s16x8 s; } c;
    c.u.x = pack2(lo.x, lo.y); c.u.y = pack2(lo.z, lo.w);
    c.u.z = pack2(hi.x, hi.y); c.u.w = pack2(hi.z, hi.w);
    return c.s;
}
__device__ __forceinline__ short bftrunc(float x) {
    return (short)(__float_as_uint(x) >> 16);
}
__device__ __forceinline__ float silu_(float v) { return v / (1.0f + __expf(-v)); }

__global__ __launch_bounds__(BLK, 4) void funcert_kernel(
    const float* __restrict__ nf,
    const float* __restrict__ energy,
    const float* __restrict__ forces,
    const float* __restrict__ stress,
    const float* __restrict__ W1f, const float* __restrict__ b1f,
    const float* __restrict__ W2f, const float* __restrict__ b2f,
    const float* __restrict__ W3f, const float* __restrict__ b3f,
    float* __restrict__ out)
{
    const int t   = threadIdx.x;
    const int gid = blockIdx.x * BLK + t;

    // double-buffered quarter tiles (64 atoms x 64 bf16 ch) + h1
    __shared__ short Xq[2][64 * 64];   // 2 x 8 KB
    __shared__ short H1s[64 * 64];     // 8 KB

    const int lane  = t & 63;
    const int w     = t >> 6;
    const int g     = lane >> 4;       // k-subgroup
    const int col   = lane & 15;       // A row / B col / D col
    const int abase = blockIdx.x * 64;
    const int ch    = w * 16 + col;

    // staging map: thread -> (row_base = t>>4, f4c = t&15); rows row_base+16i
    const int rb  = t >> 4;
    const int f4c = t & 15;
    const float4* nfr = (const float4*)nf + (size_t)(abase + rb) * 96 + f4c;
    // quarter q covers logical f4 cols [16q,16q+16); global base:
    //   q0->0, q1->16, q2->64, q3->80  (concat skips f4 cols [32,64))
    // LDS write byte offset (involution slot swizzle, matches read side):
    const int wbyte0 = rb * 128 + (f4c & 1) * 8;   // + 16*((f4c>>1)^(r&7)) + i*16*128

    #define XQ_ISSUE(dst, qb)                                            \
        { _Pragma("unroll")                                              \
          for (int i = 0; i < 4; ++i)                                    \
              dst[i] = *(const f32x4*)(nfr + (size_t)i * 16 * 96 + (qb)); }

    #define XQ_STASH(buf, src)                                           \
        { _Pragma("unroll")                                              \
          for (int i = 0; i < 4; ++i) {                                  \
              const int r = rb + 16 * i;                                 \
              u32x2 bb;                                                  \
              bb.x = pack2(src[i].x, src[i].y);                          \
              bb.y = pack2(src[i].z, src[i].w);                          \
              *(u32x2*)((char*)(buf) + (wbyte0 + 2048 * i +              \
                        ((((f4c >> 1) ^ (r & 7))) << 4))) = bb;          \
          } }

    #define WQ_ISSUE(dst, q)                                             \
        { _Pragma("unroll")                                              \
          for (int ks2 = 0; ks2 < 2; ++ks2) {                            \
              const float* p = W1f + ch * 256 + (q) * 64 + ks2 * 32 + g * 8; \
              dst[2 * ks2]     = *(const f32x4*)p;                       \
              dst[2 * ks2 + 1] = *(const f32x4*)(p + 4);                 \
          } }

    #define Q_COMPUTE(buf, wf)                                           \
        { _Pragma("unroll")                                              \
          for (int mt = 0; mt < 4; ++mt) {                               \
              const int row = mt * 16 + col;                             \
              _Pragma("unroll")                                          \
              for (int ks2 = 0; ks2 < 2; ++ks2) {                        \
                  const int sl = (ks2 * 4 + g) ^ (row & 7);              \
                  const s16x8 af = *(const s16x8*)((buf) + row * 64 + sl * 8); \
                  acc[mt] = __builtin_amdgcn_mfma_f32_16x16x32_bf16(af, wf[ks2], acc[mt], 0, 0, 0); \
              } } }

    f32x4 xa[4], xb[4], wv[4];
    s16x8 wf[2];
    f32x4 acc[4];
    #pragma unroll
    for (int mt = 0; mt < 4; ++mt) acc[mt] = (f32x4){0.f, 0.f, 0.f, 0.f};

    // ---- prologue: get 2 quarters of X + Q0's W in flight immediately ----
    XQ_ISSUE(xa, 0);          // XQ0
    XQ_ISSUE(xb, 16);         // XQ1
    WQ_ISSUE(wv, 0);          // WQ0

    // passthrough / constant outputs as float4 (load issues now, store async)
    if (gid < 40960) {
        f32x4 v; int o = gid;
        if      (gid < 128)   { v = ((const f32x4*)energy)[gid]; }
        else if (gid < 38528) { v = ((const f32x4*)forces)[gid - 128]; }
        else if (gid < 39680) { v = ((const f32x4*)stress)[gid - 38528]; }
        else if (gid < 39808) { v = (f32x4){0.6f, 0.6f, 0.6f, 0.6f}; }
        else { v = (f32x4){0.00625f, 0.00625f, 0.00625f, 0.00625f}; o = gid + 38400; }
        ((f32x4*)out)[o] = v;
    }
    const float b1v = b1f[ch];

    // ---- Q0: stash (waits only XQ0) -> barrier -> prefetch XQ2/WQ1 -> compute
    wf[0] = pack8(wv[0], wv[1]); wf[1] = pack8(wv[2], wv[3]);
    XQ_STASH(Xq[0], xa);
    __syncthreads();                     // buf0 ready
    XQ_ISSUE(xa, 64);                    // XQ2 (reuses xa)
    WQ_ISSUE(wv, 1);                     // WQ1
    Q_COMPUTE(Xq[0], wf);
    __syncthreads();                     // all waves done reading buf0

    // ---- Q1 ----
    wf[0] = pack8(wv[0], wv[1]); wf[1] = pack8(wv[2], wv[3]);
    XQ_STASH(Xq[1], xb);                 // waits XQ1 (long since arrived)
    __syncthreads();                     // buf1 ready
    XQ_ISSUE(xb, 80);                    // XQ3
    WQ_ISSUE(wv, 2);                     // WQ2
    Q_COMPUTE(Xq[1], wf);
    __syncthreads();                     // done reading buf1

    // ---- Q2 ----
    wf[0] = pack8(wv[0], wv[1]); wf[1] = pack8(wv[2], wv[3]);
    XQ_STASH(Xq[0], xa);                 // waits XQ2
    __syncthreads();                     // buf0 ready
    WQ_ISSUE(wv, 3);                     // WQ3
    Q_COMPUTE(Xq[0], wf);
    __syncthreads();                     // done reading buf0

    // ---- Q3 ----
    wf[0] = pack8(wv[0], wv[1]); wf[1] = pack8(wv[2], wv[3]);
    XQ_STASH(Xq[1], xb);                 // waits XQ3
    __syncthreads();                     // buf1 ready
    Q_COMPUTE(Xq[1], wf);

    // ---- bias + silu -> h1 (layout identical to R8/R10) ----
    #pragma unroll
    for (int mt = 0; mt < 4; ++mt) {
        #pragma unroll
        for (int r = 0; r < 4; ++r) {
            const int atom = mt * 16 + g * 4 + r;
            H1s[atom * 64 + ch] = bftrunc(silu_(acc[mt][r] + b1v));
        }
    }
    __syncthreads();

    // ---- L2: wave w -> atoms [16w,16w+16), 2 k-steps over 64 ch ----
    s16x8 w2frag[2];
    #pragma unroll
    for (int ks = 0; ks < 2; ++ks) {
        const float* p = W2f + col * 64 + ks * 32 + g * 8;   // B2[k][n] = W2f[n][k]
        w2frag[ks] = pack8(*(const f32x4*)p, *(const f32x4*)(p + 4));
    }
    const int arow = w * 16 + col;
    f32x4 a2 = {0.f, 0.f, 0.f, 0.f};
    #pragma unroll
    for (int ks = 0; ks < 2; ++ks) {
        const s16x8 af = *(const s16x8*)(H1s + arow * 64 + ks * 32 + g * 8);
        a2 = __builtin_amdgcn_mfma_f32_16x16x32_bf16(af, w2frag[ks], a2, 0, 0, 0);
    }

    // ---- h2 + L3 + exp: lane owns ch2=col for atoms 16w + g*4 + r ----
    const float b2v = b2f[col];
    const float w3v = W3f[col];
    float y[4];
    #pragma unroll
    for (int r = 0; r < 4; ++r)
        y[r] = silu_(a2[r] + b2v) * w3v;
    #pragma unroll
    for (int m = 1; m < 16; m <<= 1) {
        #pragma unroll
        for (int r = 0; r < 4; ++r)
            y[r] += __shfl_xor(y[r], m, 64);   // reduce over 16 cols
    }
    const float b3v = b3f[0];
    float fu[4];
    #pragma unroll
    for (int r = 0; r < 4; ++r)
        fu[r] = __expf(y[r] + b3v) * 0.1f;

    if (col < 12) {                            // 4 atoms x 3 comps per 16-lane group
        const int a_ = col / 3, c = col - a_ * 3;
        const float v = (a_ == 0) ? fu[0] : (a_ == 1) ? fu[1] : (a_ == 2) ? fu[2] : fu[3];
        const int atom = w * 16 + g * 4 + a_;
        out[OUT_FUNC + 3 * (abase + atom) + c] = v;
    }
}

extern "C" void kernel_launch(void* const* d_in, const int* in_sizes, int n_in,
                              void* d_out, int out_size, void* d_ws, size_t ws_size,
                              hipStream_t stream) {
    const float* nf     = (const float*)d_in[0];
    const float* energy = (const float*)d_in[1];
    const float* forces = (const float*)d_in[2];
    const float* stress = (const float*)d_in[3];
    const float* W1f    = (const float*)d_in[10];
    const float* b1f    = (const float*)d_in[11];
    const float* W2f    = (const float*)d_in[12];
    const float* b2f    = (const float*)d_in[13];
    const float* W3f    = (const float*)d_in[14];
    const float* b3f    = (const float*)d_in[15];
    float* out = (float*)d_out;

    dim3 grid(N_ATOMS / 64);   // 800 blocks
    funcert_kernel<<<grid, BLK, 0, stream>>>(nf, energy, forces, stress,
                                             W1f, b1f, W2f, b2f, W3f, b3f, out);
}